// Round 6
// baseline (573.101 us; speedup 1.0000x reference)
//
#include <hip/hip_runtime.h>
#include <math.h>

// Problem constants
#define GS   29
#define GS2  841
#define NCP  24389            // 29^3 control points
#define DW   15
#define PP   225              // DW^2 displacements
#define CH   675              // PP*3 channels per control point
#define CHP  676              // padded channel stride (even -> half2 vectorizable)
#define CC   8                // feature channels
#define VV   64               // volume side
#define V3   262144           // 64^3

#define ZS2  (GS2 * CHP / 2)  // plane stride in half2 units  = 284258
#define YS2  (GS  * CHP / 2)  // y-row stride in half2 units  = 9802

typedef __attribute__((ext_vector_type(8))) _Float16 half8;
typedef __attribute__((ext_vector_type(2))) _Float16 half2t;

__device__ __forceinline__ float sv(int i) {
    // DR * ((2i+1)/DW - 1)
    return 0.4f * ((2.f * i + 1.f) * (1.f / 15.f) - 1.f);
}

// fast-axis adjacent PAIR: base index + pair weights (replication clamp, exact)
__device__ __forceinline__ void axis_pair(float g, int& p0, float& wA, float& wB) {
    float i = 0.5f * ((g + 1.f) * VV - 1.f);
    float f0 = floorf(i);
    float fr = i - f0;
    int i0 = (int)f0;
    p0 = min(max(i0, 0), VV - 2);
    wA = (i0 < 0) ? 1.f : ((i0 >= VV - 1) ? 0.f : (1.f - fr));
    wB = 1.f - wA;
}
// clamped two-corner axis
__device__ __forceinline__ void axis_cl(float g, int& c0, int& c1, float& w0, float& w1) {
    float i = 0.5f * ((g + 1.f) * VV - 1.f);
    float f0 = floorf(i);
    float fr = i - f0;
    int i0 = (int)f0;
    c0 = min(max(i0, 0), VV - 1);
    c1 = min(max(i0 + 1, 0), VV - 1);
    w0 = 1.f - fr; w1 = fr;
}

__device__ __forceinline__ float sample_ssd(const _Float16* __restrict__ vol, half8 f8,
                                            int w0c, int w1c, float ww0, float ww1,
                                            int v0c, int v1c, float wv0, float wv1,
                                            int p0, float wA, float wB) {
    half8 acc = {0, 0, 0, 0, 0, 0, 0, 0};
#define PAIR_(WC, VC, WGT) {                                              \
        float fA_ = (WGT) * wA, fB_ = (WGT) * wB;                         \
        _Float16 hA_ = (_Float16)fA_, hB_ = (_Float16)fB_;                \
        half8 hA8 = {hA_, hA_, hA_, hA_, hA_, hA_, hA_, hA_};             \
        half8 hB8 = {hB_, hB_, hB_, hB_, hB_, hB_, hB_, hB_};             \
        const _Float16* vp = vol + (size_t)((((WC) * VV) + (VC)) * VV + p0) * 8; \
        half8 lo = *(const half8*)vp;                                     \
        half8 hi = *(const half8*)(vp + 8);                               \
        acc += hA8 * lo;                                                  \
        acc += hB8 * hi;                                                  \
    }
    PAIR_(w0c, v0c, ww0 * wv0)
    PAIR_(w0c, v1c, ww0 * wv1)
    PAIR_(w1c, v0c, ww1 * wv0)
    PAIR_(w1c, v1c, ww1 * wv1)
#undef PAIR_
    half8 d8 = f8 - acc;
    float ssd = 0.f;
#pragma unroll
    for (int c = 0; c < 8; c++) { float dc = (float)d8[c]; ssd = fmaf(dc, dc, ssd); }
    return ssd;
}

// feat50 (C,D,H,W) fp32 -> two fp16 channel-last volumes:
//   volA: (z,y,x,c)  x fastest   for k=0,1 (lane sweep = x)
//   volB: (z,x,y,c)  y fastest   for k=2   (lane sweep = y)
__global__ __launch_bounds__(256) void make_vols(const float* __restrict__ in,
                                                 _Float16* __restrict__ volA,
                                                 _Float16* __restrict__ volB) {
    int v = blockIdx.x * 256 + threadIdx.x;
    if (v >= V3) return;
    int z = v >> 12, y = (v >> 6) & 63, x = v & 63;
    half8 h;
#pragma unroll
    for (int c = 0; c < CC; c++) h[c] = (_Float16)in[c * V3 + v];
    *(half8*)(volA + (size_t)v * 8) = h;
    *(half8*)(volB + (size_t)((((z << 6) | x) << 6) | y) * 8) = h;
}

// Block per n. Lane p (<225) samples all 3 planes with shared-axis precompute,
// builds the (p*3+k) pdd row in LDS, fuses the first min3x3->avg3x3 pool,
// writes both rows (padded stride CHP) as fp16.
__global__ __launch_bounds__(256) void pdd_pool_n(const float* __restrict__ f00,
                                                  const _Float16* __restrict__ volA,
                                                  const _Float16* __restrict__ volB,
                                                  const float* __restrict__ grid,
                                                  const float* __restrict__ alpha,
                                                  _Float16* __restrict__ pdd,    // (n, CHP)
                                                  _Float16* __restrict__ pool) { // (n, CHP)
    int n = blockIdx.x;
    int tid = threadIdx.x;
    __shared__ __align__(16) _Float16 fixh[8];
    __shared__ float rowp[CH];
    __shared__ float smin[3 * 306];      // 17x17 per k, row pitch 18 (conflict pad)

    float gx = grid[n * 3 + 0], gy = grid[n * 3 + 1], gz = grid[n * 3 + 2];

    if (tid < 8) {
        // trilerp feat00 channel tid at grid point, padding_mode='zeros' (fp32)
        float ix = 0.5f * ((gx + 1.f) * VV - 1.f);
        float iy = 0.5f * ((gy + 1.f) * VV - 1.f);
        float iz = 0.5f * ((gz + 1.f) * VV - 1.f);
        float x0f = floorf(ix), y0f = floorf(iy), z0f = floorf(iz);
        float fx = ix - x0f, fy = iy - y0f, fz = iz - z0f;
        int x0 = (int)x0f, y0 = (int)y0f, z0 = (int)z0f;
        const float* fc = f00 + tid * V3;
        float acc = 0.f;
        for (int dz = 0; dz < 2; dz++) {
            int zi = z0 + dz; float wz = dz ? fz : 1.f - fz;
            for (int dy = 0; dy < 2; dy++) {
                int yi = y0 + dy; float wy = dy ? fy : 1.f - fy;
                for (int dx = 0; dx < 2; dx++) {
                    int xi = x0 + dx; float wx = dx ? fx : 1.f - fx;
                    if (xi >= 0 && xi < VV && yi >= 0 && yi < VV && zi >= 0 && zi < VV)
                        acc += wx * wy * wz * fc[(zi * VV + yi) * VV + xi];
                }
            }
        }
        fixh[tid] = (_Float16)acc;
    }
    __syncthreads();

    if (tid < PP) {
        int h_ = tid / 15, w_ = tid - 15 * h_;
        float A = sv(h_), B = sv(w_);
        half8 f8 = *(const half8*)fixh;
        float a0 = alpha[0], a1 = alpha[1];

        // shared axes: k0/k1 share u=gx+B; k1/k2 share w=gz+A; uniforms gz,gy,gx
        int px0; float pxA, pxB; axis_pair(gx + B, px0, pxA, pxB);   // u for k0,k1 (volA x)
        int py0; float pyA, pyB; axis_pair(gy + B, py0, pyA, pyB);   // u for k2   (volB y)
        int va0, va1; float wva0, wva1; axis_cl(gy + A, va0, va1, wva0, wva1); // v k0
        int wa0, wa1; float wwa0, wwa1; axis_cl(gz + A, wa0, wa1, wwa0, wwa1); // w k1,k2
        int zb0, zb1; float wzb0, wzb1; axis_cl(gz, zb0, zb1, wzb0, wzb1);     // w k0
        int yb0, yb1; float wyb0, wyb1; axis_cl(gy, yb0, yb1, wyb0, wyb1);     // v k1
        int xb0, xb1; float wxb0, wxb1; axis_cl(gx, xb0, xb1, wxb0, wxb1);     // v k2

        rowp[tid * 3 + 0] = a1 + a0 * sample_ssd(volA, f8, zb0, zb1, wzb0, wzb1,
                                                 va0, va1, wva0, wva1, px0, pxA, pxB);
        rowp[tid * 3 + 1] = a1 + a0 * sample_ssd(volA, f8, wa0, wa1, wwa0, wwa1,
                                                 yb0, yb1, wyb0, wyb1, px0, pxA, pxB);
        rowp[tid * 3 + 2] = a1 + a0 * sample_ssd(volB, f8, wa0, wa1, wwa0, wwa1,
                                                 xb0, xb1, wxb0, wxb1, py0, pyA, pyB);
    }
    __syncthreads();

    // min3x3 over pad-2 edge-clamped 15x15, per k: 3*17*17 outputs (pitch-18 smin)
    for (int idx = tid; idx < 867; idx += 256) {
        int k = idx / 289; int r = idx - 289 * k; int a = r / 17; int b = r - 17 * a;
        float mn = 1e30f;
        for (int u = 0; u < 3; u++) {
            int hh = min(max(a + u - 2, 0), 14);
            for (int v = 0; v < 3; v++) {
                int ww = min(max(b + v - 2, 0), 14);
                mn = fminf(mn, rowp[(hh * 15 + ww) * 3 + k]);
            }
        }
        smin[k * 306 + a * 18 + b] = mn;
    }
    __syncthreads();

    for (int i = tid; i < CH; i += 256) {
        pdd[(size_t)n * CHP + i] = (_Float16)rowp[i];
        int p = i / 3, k = i - 3 * p;              // i = p*3+k
        int h = p / 15, w = p - 15 * h;
        float acc = 0.f;
        for (int a = 0; a < 3; a++)
            for (int b = 0; b < 3; b++)
                acc += smin[k * 306 + (h + a) * 18 + (w + b)];
        pool[(size_t)n * CHP + i] = (_Float16)(acc * (1.f / 9.f));
    }
}

// 5-tap triangle [1,2,3,2,1]/9 along z, sliding window, half2 lanes.
__global__ __launch_bounds__(256) void gs_z2v(const half2t* __restrict__ in,
                                              half2t* __restrict__ out) {
    int id = blockIdx.x * 256 + threadIdx.x;
    if (id >= ZS2) return;
    const float w0 = 1.f / 9.f, w1 = 2.f / 9.f, w2 = 3.f / 9.f;
    const half2t* p = in + id;
    half2t h0 = p[0], h3 = p[ZS2], h4 = p[2 * (size_t)ZS2];
    float a0 = (float)h0[0], b0 = (float)h0[1];
    float a1 = a0, b1 = b0, a2 = a0, b2 = b0;
    float a3 = (float)h3[0], b3 = (float)h3[1];
    float a4 = (float)h4[0], b4 = (float)h4[1];
    for (int z = 0; z < GS; z++) {
        half2t o;
        o[0] = (_Float16)(w0 * a0 + w1 * a1 + w2 * a2 + w1 * a3 + w0 * a4);
        o[1] = (_Float16)(w0 * b0 + w1 * b1 + w2 * b2 + w1 * b3 + w0 * b4);
        out[id + (size_t)z * ZS2] = o;
        a0 = a1; b0 = b1; a1 = a2; b1 = b2; a2 = a3; b2 = b3; a3 = a4; b3 = b4;
        int zn = z + 3; if (zn > GS - 1) zn = GS - 1;
        half2t hn = p[(size_t)zn * ZS2];
        a4 = (float)hn[0]; b4 = (float)hn[1];
    }
}

// y-pass fused with cost = a4 + a2*pdd + a3*gs (RMW on pc), half2 lanes.
__global__ __launch_bounds__(256) void gs_y_cost2v(const half2t* __restrict__ zt,
                                                   half2t* pc,
                                                   const float* __restrict__ alpha) {
    int id = blockIdx.x * 256 + threadIdx.x;
    if (id >= GS * YS2) return;
    int z = id / YS2; int rem = id - z * YS2;
    size_t base = (size_t)z * ZS2 + rem;
    const float w0 = 1.f / 9.f, w1 = 2.f / 9.f, w2 = 3.f / 9.f;
    float c2 = alpha[2], c3 = alpha[3], c4 = alpha[4];
    const half2t* p = zt + base;
    half2t h0 = p[0], h3 = p[YS2], h4 = p[2 * (size_t)YS2];
    float a0 = (float)h0[0], b0 = (float)h0[1];
    float a1 = a0, b1 = b0, a2 = a0, b2 = b0;
    float a3 = (float)h3[0], b3 = (float)h3[1];
    float a4 = (float)h4[0], b4 = (float)h4[1];
    for (int y = 0; y < GS; y++) {
        size_t idx = base + (size_t)y * YS2;
        float sA = w0 * a0 + w1 * a1 + w2 * a2 + w1 * a3 + w0 * a4;
        float sB = w0 * b0 + w1 * b1 + w2 * b2 + w1 * b3 + w0 * b4;
        half2t cur = pc[idx];
        half2t o;
        o[0] = (_Float16)(c4 + c2 * (float)cur[0] + c3 * sA);
        o[1] = (_Float16)(c4 + c2 * (float)cur[1] + c3 * sB);
        pc[idx] = o;
        a0 = a1; b0 = b1; a1 = a2; b1 = b2; a2 = a3; b2 = b3; a3 = a4; b3 = b4;
        int yn = y + 3; if (yn > GS - 1) yn = GS - 1;
        half2t hn = p[(size_t)yn * YS2];
        a4 = (float)hn[0]; b4 = (float)hn[1];
    }
}

// plain y-pass, half2 fp16 out (final grid_smooth)
__global__ __launch_bounds__(256) void gs_y2v(const half2t* __restrict__ zt,
                                              half2t* __restrict__ out) {
    int id = blockIdx.x * 256 + threadIdx.x;
    if (id >= GS * YS2) return;
    int z = id / YS2; int rem = id - z * YS2;
    size_t base = (size_t)z * ZS2 + rem;
    const float w0 = 1.f / 9.f, w1 = 2.f / 9.f, w2 = 3.f / 9.f;
    const half2t* p = zt + base;
    half2t h0 = p[0], h3 = p[YS2], h4 = p[2 * (size_t)YS2];
    float a0 = (float)h0[0], b0 = (float)h0[1];
    float a1 = a0, b1 = b0, a2 = a0, b2 = b0;
    float a3 = (float)h3[0], b3 = (float)h3[1];
    float a4 = (float)h4[0], b4 = (float)h4[1];
    for (int y = 0; y < GS; y++) {
        half2t o;
        o[0] = (_Float16)(w0 * a0 + w1 * a1 + w2 * a2 + w1 * a3 + w0 * a4);
        o[1] = (_Float16)(w0 * b0 + w1 * b1 + w2 * b2 + w1 * b3 + w0 * b4);
        out[base + (size_t)y * YS2] = o;
        a0 = a1; b0 = b1; a1 = a2; b1 = b2; a2 = a3; b2 = b3; a3 = a4; b3 = b4;
        int yn = y + 3; if (yn > GS - 1) yn = GS - 1;
        half2t hn = p[(size_t)yn * YS2];
        a4 = (float)hn[0]; b4 = (float)hn[1];
    }
}

// Second pool (original layout, padded stride, half2 reads)
__global__ __launch_bounds__(256) void pool_h(const _Float16* __restrict__ in,
                                              _Float16* __restrict__ out) {
    int n = blockIdx.x;
    int tid = threadIdx.x;
    __shared__ float sin_[CHP];
    __shared__ float smn[3 * 306];
    const half2t* inr = (const half2t*)(in + (size_t)n * CHP);
    for (int i2 = tid; i2 < CHP / 2; i2 += 256) {
        half2t h = inr[i2];
        sin_[2 * i2] = (float)h[0];
        sin_[2 * i2 + 1] = (float)h[1];
    }
    __syncthreads();
    for (int idx = tid; idx < 867; idx += 256) {
        int k = idx / 289; int r = idx - 289 * k; int a = r / 17; int b = r - 17 * a;
        float mn = 1e30f;
        for (int u = 0; u < 3; u++) {
            int hh = min(max(a + u - 2, 0), 14);
            for (int v = 0; v < 3; v++) {
                int ww = min(max(b + v - 2, 0), 14);
                mn = fminf(mn, sin_[(hh * 15 + ww) * 3 + k]);
            }
        }
        smn[k * 306 + a * 18 + b] = mn;
    }
    __syncthreads();
    for (int s = tid; s < CH; s += 256) {
        int p = s / 3, k = s - 3 * p;
        int h = p / 15, w = p - 15 * h;
        float acc = 0.f;
        for (int a = 0; a < 3; a++)
            for (int b = 0; b < 3; b++)
                acc += smn[k * 306 + (h + a) * 18 + (w + b)];
        out[(size_t)n * CHP + s] = (_Float16)(acc * (1.f / 9.f));
    }
}

// softmax over p (per n,k) + pred einsum; reads padded fp16 cost_avg,
// writes cost_soft, pred_xyz, cost_avg (all fp32, original layout).
__global__ __launch_bounds__(256) void softmax_pred3(const _Float16* __restrict__ ca,
                                                     const float* __restrict__ alpha,
                                                     float* __restrict__ soft,
                                                     float* __restrict__ pred,
                                                     float* __restrict__ cavg) {
    int n = blockIdx.x;
    int tid = threadIdx.x;
    int wave = tid >> 6, lane = tid & 63;
    __shared__ float vals[CHP];   // raw cost_avg
    __shared__ float sfx[CH];     // softmax result
    __shared__ float partial[3][3];
    const half2t* inr = (const half2t*)(ca + (size_t)n * CHP);
    for (int i2 = tid; i2 < CHP / 2; i2 += 256) {
        half2t h = inr[i2];
        vals[2 * i2] = (float)h[0];
        vals[2 * i2 + 1] = (float)h[1];
    }
    __syncthreads();
    float a5 = alpha[5];
    if (wave < 3) {
        int k = wave;
        float v[4], e[4];
        float m = -1e30f;
#pragma unroll
        for (int j = 0; j < 4; j++) {
            int p = lane + 64 * j;
            v[j] = (p < PP) ? -a5 * vals[p * 3 + k] : -1e30f;
            m = fmaxf(m, v[j]);
        }
#pragma unroll
        for (int o = 32; o > 0; o >>= 1) m = fmaxf(m, __shfl_xor(m, o));
        float sum = 0.f;
#pragma unroll
        for (int j = 0; j < 4; j++) {
            int p = lane + 64 * j;
            e[j] = (p < PP) ? __expf(v[j] - m) : 0.f;
            sum += e[j];
        }
#pragma unroll
        for (int o = 32; o > 0; o >>= 1) sum += __shfl_xor(sum, o);
        float inv = 1.f / sum;
        float px = 0.f, py = 0.f, pz = 0.f;
#pragma unroll
        for (int j = 0; j < 4; j++) {
            int p = lane + 64 * j;
            if (p < PP) {
                float s = e[j] * inv;
                sfx[p * 3 + k] = s;
                int h_ = p / 15, w_ = p - 15 * h_;
                float A = sv(h_), B = sv(w_);
                if (k == 0)      { px += s * B; py += s * A; }
                else if (k == 1) { px += s * B; pz += s * A; }
                else             { py += s * B; pz += s * A; }
            }
        }
#pragma unroll
        for (int o = 32; o > 0; o >>= 1) {
            px += __shfl_xor(px, o);
            py += __shfl_xor(py, o);
            pz += __shfl_xor(pz, o);
        }
        if (lane == 0) { partial[k][0] = px; partial[k][1] = py; partial[k][2] = pz; }
    }
    __syncthreads();
    if (tid < 3) pred[(size_t)n * 3 + tid] = 0.5f * (partial[0][tid] + partial[1][tid] + partial[2][tid]);
    for (int i = tid; i < CH; i += 256) {
        soft[(size_t)n * CH + i] = sfx[i];
        cavg[(size_t)n * CH + i] = vals[i];
    }
}

extern "C" void kernel_launch(void* const* d_in, const int* in_sizes, int n_in,
                              void* d_out, int out_size, void* d_ws, size_t ws_size,
                              hipStream_t stream) {
    const float* f00   = (const float*)d_in[0];
    const float* f50   = (const float*)d_in[1];
    // d_in[2] (shift_2d_min) broadcast of shift_2d -- unused
    const float* grid  = (const float*)d_in[3];
    // d_in[4] (shift_2d) recomputed analytically -- unused
    const float* alpha = (const float*)d_in[5];

    float* out0 = (float*)d_out;                   // cost_soft  (N*675)
    float* out1 = out0 + (size_t)NCP * CH;         // pred_xyz   (N*3)
    float* out2 = out1 + (size_t)NCP * 3;          // cost_avg   (N*675)

    char* ws = (char*)d_ws;
    _Float16* volA = (_Float16*)ws;                          // 4MB
    _Float16* volB = volA + (size_t)V3 * 8;                  // 4MB
    _Float16* H0 = volB + (size_t)V3 * 8;                    // N*CHP fp16
    _Float16* H1 = H0 + (size_t)NCP * CHP;                   // N*CHP fp16
    _Float16* H2 = H1 + (size_t)NCP * CHP;                   // N*CHP fp16

    make_vols<<<(V3 + 255) / 256, 256, 0, stream>>>(f50, volA, volB);

    // pdd + pool1 fused, original (p*3+k) rows, padded fp16 stride
    pdd_pool_n<<<NCP, 256, 0, stream>>>(f00, volA, volB, grid, alpha, H0, H1);

    const int gbv = (ZS2 + 255) / 256;   // 284258 half2 lanes per pass

    gs_z2v<<<gbv, 256, 0, stream>>>((const half2t*)H1, (half2t*)H2);
    gs_y_cost2v<<<gbv, 256, 0, stream>>>((const half2t*)H2, (half2t*)H0, alpha);  // cost in H0

    pool_h<<<NCP, 256, 0, stream>>>(H0, H1);
    gs_z2v<<<gbv, 256, 0, stream>>>((const half2t*)H1, (half2t*)H2);
    gs_y2v<<<gbv, 256, 0, stream>>>((const half2t*)H2, (half2t*)H1);              // cost_avg fp16 in H1

    softmax_pred3<<<NCP, 256, 0, stream>>>(H1, alpha, out0, out1, out2);
}